// Round 1
// baseline (5215.216 us; speedup 1.0000x reference)
//
#include <hip/hip_runtime.h>
#include <hip/hip_bf16.h>
#include <math.h>

#define BB 64
#define TT 256
#define LCH 16
#define DC 50
#define CHN 100
#define DW 300
#define DF 20
#define HID 256
#define G4 1024
#define INDIM 420
#define NTAG 52
#define TSTART 50
#define TSTOP 51

// ------------------- workspace layout (bytes) -------------------
// region0 (reused): pooled[16384*100 f32] + x[16384*420 f32]  -> later h_f, h_b
static constexpr size_t OFF_POOL  = 0;                       // 6,553,600
static constexpr size_t OFF_X     = 6553600;                 // 27,525,120 -> end 34,078,720
static constexpr size_t OFF_HF    = 0;                       // 16,777,216 (overlaps pooled+x, dead by then)
static constexpr size_t OFF_HB    = 16777216;                // 16,777,216 -> 33,554,432
static constexpr size_t OFF_XSF   = 34078720;                // 67,108,864
static constexpr size_t OFF_XSB   = 101187584;               // 67,108,864 -> 168,296,448
static constexpr size_t OFF_FEATS = 168296448;               // 3,407,872  -> 171,704,320
static constexpr size_t OFF_WPF   = 171704320;               // 1,048,576
static constexpr size_t OFF_WPB   = 172752896;               // 1,048,576
static constexpr size_t OFF_LOSSB = 173801472;               // 256

__device__ __forceinline__ float sigm(float x) { return 1.0f / (1.0f + expf(-x)); }

// ---- pack W_hh (1024x256 row-major) -> Wp[kc=32][row=1024][8] for coalesced LSTM loads
__global__ void k_pack(const float* __restrict__ w, float* __restrict__ wp) {
    int e = blockIdx.x * 256 + threadIdx.x;         // 0..262143
    if (e >= 32 * 1024 * 8) return;
    int kc = e >> 13;
    int rem = e & 8191;
    int r = rem >> 3;
    int jj = rem & 7;
    wp[e] = w[r * HID + kc * 8 + jj];
}

// ---- char CNN: one block (128 thr) per word; conv k=3 pad=1 over L=16, maxpool
__global__ __launch_bounds__(128) void k_charcnn(const int* __restrict__ bchar,
                                                 const float* __restrict__ cemb,
                                                 const float* __restrict__ cw,
                                                 const float* __restrict__ cb,
                                                 float* __restrict__ pooled) {
    __shared__ float ET[DC][20];   // transposed emb with halo cols 0 and 17 = 0; stride 20 (16B-aligned rows)
    __shared__ int ids[LCH];
    int w = blockIdx.x;
    int tid = threadIdx.x;
    if (tid < LCH) ids[tid] = bchar[w * LCH + tid];
    __syncthreads();
    for (int s = tid; s < DC * 18; s += 128) {
        int d = s / 18, l = s % 18;
        float v = 0.f;
        if (l >= 1 && l <= 16) v = cemb[ids[l - 1] * DC + d];
        ET[d][l] = v;
    }
    __syncthreads();
    if (tid < CHN) {
        float acc[16];
#pragma unroll
        for (int l = 0; l < 16; l++) acc[l] = 0.f;
        for (int d = 0; d < DC; d++) {
            float e[18];
            float4 t0 = *(const float4*)&ET[d][0];
            float4 t1 = *(const float4*)&ET[d][4];
            float4 t2 = *(const float4*)&ET[d][8];
            float4 t3 = *(const float4*)&ET[d][12];
            e[0]=t0.x; e[1]=t0.y; e[2]=t0.z; e[3]=t0.w;
            e[4]=t1.x; e[5]=t1.y; e[6]=t1.z; e[7]=t1.w;
            e[8]=t2.x; e[9]=t2.y; e[10]=t2.z; e[11]=t2.w;
            e[12]=t3.x; e[13]=t3.y; e[14]=t3.z; e[15]=t3.w;
            e[16]=ET[d][16]; e[17]=ET[d][17];
            float w0 = cw[(tid * DC + d) * 3 + 0];
            float w1 = cw[(tid * DC + d) * 3 + 1];
            float w2 = cw[(tid * DC + d) * 3 + 2];
#pragma unroll
            for (int l = 0; l < 16; l++)
                acc[l] += w0 * e[l] + w1 * e[l + 1] + w2 * e[l + 2];
        }
        float m = acc[0];
#pragma unroll
        for (int l = 1; l < 16; l++) m = fmaxf(m, acc[l]);
        pooled[w * CHN + tid] = m + cb[tid];
    }
}

// ---- assemble x[16384][420] = [word_emb | char_feats(recovered) | feat_emb]
__global__ __launch_bounds__(128) void k_concat(const int* __restrict__ word,
                                                const int* __restrict__ featsidx,
                                                const int* __restrict__ recover,
                                                const float* __restrict__ wemb,
                                                const float* __restrict__ femb,
                                                const float* __restrict__ pooled,
                                                float* __restrict__ x) {
    int w = blockIdx.x;
    int tid = threadIdx.x;
    int b = w >> 8;
    int wid = word[w];
    for (int c = tid; c < DW; c += 128) x[(size_t)w * INDIM + c] = wemb[(size_t)wid * DW + c];
    int rc = recover[w];
    if (tid < CHN) x[(size_t)w * INDIM + DW + tid] = pooled[rc * CHN + tid];
    if (tid < DF)  x[(size_t)w * INDIM + DW + CHN + tid] = femb[featsidx[b] * DF + tid];
}

// ---- fp32 GEMM: C[m][g] = sum_k A[m][k]*W[g][k] + bias[g];  M=16384 N=1024 K=420
#define BM 128
#define BN 64
#define BK 16
__global__ __launch_bounds__(256) void k_gemm(const float* __restrict__ A,
                                              const float* __restrict__ Wt,
                                              const float* __restrict__ bias,
                                              float* __restrict__ C) {
    __shared__ float As[BK][BM];
    __shared__ float Bs[BK][BN];
    int tid = threadIdx.x;
    int tx = tid & 15, ty = tid >> 4;
    int m0 = blockIdx.y * BM, n0 = blockIdx.x * BN;
    float acc[8][4];
#pragma unroll
    for (int i = 0; i < 8; i++)
#pragma unroll
        for (int jj = 0; jj < 4; jj++) acc[i][jj] = 0.f;
    int am = tid >> 1, ak = (tid & 1) * 8;
    int bn = tid >> 2, bk = (tid & 3) * 4;
    for (int k0 = 0; k0 < INDIM; k0 += BK) {
#pragma unroll
        for (int q = 0; q < 8; q++) {
            int k = k0 + ak + q;
            As[ak + q][am] = (k < INDIM) ? A[(size_t)(m0 + am) * INDIM + k] : 0.f;
        }
#pragma unroll
        for (int q = 0; q < 4; q++) {
            int k = k0 + bk + q;
            Bs[bk + q][bn] = (k < INDIM) ? Wt[(size_t)(n0 + bn) * INDIM + k] : 0.f;
        }
        __syncthreads();
#pragma unroll
        for (int kk = 0; kk < BK; kk++) {
            float4 a0 = *(const float4*)&As[kk][ty * 8];
            float4 a1 = *(const float4*)&As[kk][ty * 8 + 4];
            float4 b0 = *(const float4*)&Bs[kk][tx * 4];
            float ra[8] = {a0.x, a0.y, a0.z, a0.w, a1.x, a1.y, a1.z, a1.w};
            float rb[4] = {b0.x, b0.y, b0.z, b0.w};
#pragma unroll
            for (int i = 0; i < 8; i++)
#pragma unroll
                for (int jj = 0; jj < 4; jj++) acc[i][jj] += ra[i] * rb[jj];
        }
        __syncthreads();
    }
    float4 bv = *(const float4*)&bias[n0 + tx * 4];
#pragma unroll
    for (int i = 0; i < 8; i++) {
        float4 o;
        o.x = acc[i][0] + bv.x; o.y = acc[i][1] + bv.y;
        o.z = acc[i][2] + bv.z; o.w = acc[i][3] + bv.w;
        *(float4*)&C[(size_t)(m0 + ty * 8 + i) * G4 + n0 + tx * 4] = o;
    }
}

// ---- masked BiLSTM: one block per (batch, dir); thread j owns hidden unit j
__global__ __launch_bounds__(256) void k_lstm(const float* __restrict__ xs_f,
                                              const float* __restrict__ xs_b,
                                              const float* __restrict__ wp_f,
                                              const float* __restrict__ wp_b,
                                              const int* __restrict__ wlen,
                                              float* __restrict__ h_f,
                                              float* __restrict__ h_b) {
    int b = blockIdx.x & 63, d = blockIdx.x >> 6;
    const float* xs = d ? xs_b : xs_f;
    const float* wp = d ? wp_b : wp_f;
    float* ho = d ? h_b : h_f;
    int len = wlen[b];
    __shared__ float hsh[HID];
    int j = threadIdx.x;
    hsh[j] = 0.f;
    float c = 0.f;
    __syncthreads();
    for (int s = 0; s < len; s++) {
        int t = d ? (len - 1 - s) : s;
        const float* xr = xs + (size_t)(b * TT + t) * G4;
        float a0 = xr[j];
        float a1 = xr[256 + j];
        float a2 = xr[512 + j];
        float a3 = xr[768 + j];
        for (int kc = 0; kc < 32; kc++) {
            const float4 h0 = *(const float4*)&hsh[kc * 8];
            const float4 h1 = *(const float4*)&hsh[kc * 8 + 4];
            const float* wr = wp + (size_t)kc * 8192;
#define ROWACC(ACC, ROFF)                                                      \
            {                                                                  \
                const float4 wa = *(const float4*)&wr[(ROFF + j) * 8];         \
                const float4 wb = *(const float4*)&wr[(ROFF + j) * 8 + 4];     \
                ACC += wa.x * h0.x + wa.y * h0.y + wa.z * h0.z + wa.w * h0.w;  \
                ACC += wb.x * h1.x + wb.y * h1.y + wb.z * h1.z + wb.w * h1.w;  \
            }
            ROWACC(a0, 0)
            ROWACC(a1, 256)
            ROWACC(a2, 512)
            ROWACC(a3, 768)
#undef ROWACC
        }
        float ig = sigm(a0), fg = sigm(a1), gg = tanhf(a2), og = sigm(a3);
        c = fg * c + ig * gg;
        float h = og * tanhf(c);
        __syncthreads();
        hsh[j] = h;
        __syncthreads();
        ho[(size_t)(b * TT + t) * HID + j] = h;
    }
}

// ---- projection: feats[w][52] = [hf|hb] . proj_w[j] + proj_b[j]
__global__ __launch_bounds__(64) void k_proj(const float* __restrict__ hf,
                                             const float* __restrict__ hb,
                                             const float* __restrict__ pw,
                                             const float* __restrict__ pb,
                                             float* __restrict__ feats) {
    __shared__ float hc[512];
    int w = blockIdx.x;
    int tid = threadIdx.x;
    {
        float4 v = *(const float4*)&hf[(size_t)w * HID + tid * 4];
        *(float4*)&hc[tid * 4] = v;
        float4 u = *(const float4*)&hb[(size_t)w * HID + tid * 4];
        *(float4*)&hc[256 + tid * 4] = u;
    }
    __syncthreads();
    if (tid < NTAG) {
        float s = pb[tid];
        for (int k = 0; k < 512; k += 4) {
            float4 h4 = *(const float4*)&hc[k];
            float4 w4 = *(const float4*)&pw[(size_t)tid * 512 + k];
            s += h4.x * w4.x + h4.y * w4.y + h4.z * w4.z + h4.w * w4.w;
        }
        feats[(size_t)w * NTAG + tid] = s;
    }
}

// ---- CRF: forward (Z), gold score, viterbi + backtrace. one block per batch
__global__ __launch_bounds__(64) void k_crf(const float* __restrict__ feats,
                                            const float* __restrict__ trans,
                                            const int* __restrict__ wlen,
                                            const int* __restrict__ blabel,
                                            float* __restrict__ lossb,
                                            float* __restrict__ outtags) {
    __shared__ float Tm[NTAG * NTAG];
    __shared__ float alpha[NTAG], valpha[NTAG], frow[NTAG], red[NTAG];
    __shared__ unsigned char bp[TT - 1][NTAG];
    int b = blockIdx.x;
    int j = threadIdx.x;
    for (int s = j; s < NTAG * NTAG; s += 64) Tm[s] = trans[s];
    __syncthreads();
    int len = wlen[b];
    const float* fb = feats + (size_t)b * TT * NTAG;
    if (j < NTAG) {
        float a = fb[j] + Tm[TSTART * NTAG + j];
        alpha[j] = a;
        valpha[j] = a;
    }
    __syncthreads();
    for (int t = 1; t < len; t++) {
        if (j < NTAG) frow[j] = fb[(size_t)t * NTAG + j];
        __syncthreads();
        float anew = 0.f, vnew = 0.f;
        int arg = 0;
        if (j < NTAG) {
            float m1 = -1e30f;
            for (int i = 0; i < NTAG; i++) m1 = fmaxf(m1, alpha[i] + Tm[i * NTAG + j]);
            float ssum = 0.f;
            for (int i = 0; i < NTAG; i++) ssum += expf(alpha[i] + Tm[i * NTAG + j] - m1);
            anew = m1 + logf(ssum) + frow[j];
            float vm = -1e30f;
            for (int i = 0; i < NTAG; i++) {
                float sv = valpha[i] + Tm[i * NTAG + j];
                if (sv > vm) { vm = sv; arg = i; }   // strict > keeps first max (jnp.argmax)
            }
            vnew = vm + frow[j];
        }
        __syncthreads();
        if (j < NTAG) {
            alpha[j] = anew;
            valpha[j] = vnew;
            bp[t - 1][j] = (unsigned char)arg;
        }
        __syncthreads();
    }
    // ---- Z + gold (thread 0) ----
    if (j < NTAG) red[j] = alpha[j] + Tm[j * NTAG + TSTOP];
    __syncthreads();
    float Zg = 0.f, goldv = 0.f;
    if (j == 0) {
        float m1 = red[0];
        for (int i = 1; i < NTAG; i++) m1 = fmaxf(m1, red[i]);
        float ssum = 0.f;
        for (int i = 0; i < NTAG; i++) ssum += expf(red[i] - m1);
        Zg = m1 + logf(ssum);
        const int* lab = blabel + b * TT;
        goldv = Tm[TSTART * NTAG + lab[0]] + fb[lab[0]];
        for (int t = 1; t < len; t++)
            goldv += Tm[lab[t - 1] * NTAG + lab[t]] + fb[(size_t)t * NTAG + lab[t]];
        goldv += Tm[lab[len - 1] * NTAG + TSTOP];
    }
    __syncthreads();
    // ---- viterbi terminal + backtrace ----
    if (j < NTAG) red[j] = valpha[j] + Tm[j * NTAG + TSTOP];
    __syncthreads();
    if (j == 0) {
        int best = 0;
        float vm = red[0];
        for (int i = 1; i < NTAG; i++)
            if (red[i] > vm) { vm = red[i]; best = i; }
        float* ot = outtags + (size_t)b * TT;
        int tag = best;
        ot[len - 1] = (float)tag;
        for (int t = len - 2; t >= 0; t--) {
            tag = bp[t][tag];
            ot[t] = (float)tag;
        }
        for (int t = len; t < TT; t++) ot[t] = 0.f;
        lossb[b] = Zg - goldv;
    }
}

// ---- deterministic final loss reduction
__global__ void k_loss(const float* __restrict__ lossb, float* __restrict__ out) {
    if (threadIdx.x == 0 && blockIdx.x == 0) {
        float s = 0.f;
        for (int i = 0; i < BB; i++) s += lossb[i];
        out[0] = s;
    }
}

extern "C" void kernel_launch(void* const* d_in, const int* in_sizes, int n_in,
                              void* d_out, int out_size, void* d_ws, size_t ws_size,
                              hipStream_t stream) {
    const int* batch_word     = (const int*)d_in[0];
    const int* batch_features = (const int*)d_in[1];
    const int* batch_wordlen  = (const int*)d_in[2];
    const int* batch_char     = (const int*)d_in[3];
    const int* batch_recover  = (const int*)d_in[5];
    const int* batch_label    = (const int*)d_in[7];
    const float* char_emb = (const float*)d_in[8];
    const float* conv_w   = (const float*)d_in[9];
    const float* conv_b   = (const float*)d_in[10];
    const float* word_emb = (const float*)d_in[11];
    const float* feat_emb = (const float*)d_in[12];
    const float* w_ih_f   = (const float*)d_in[13];
    const float* w_hh_f   = (const float*)d_in[14];
    const float* b_f      = (const float*)d_in[15];
    const float* w_ih_b   = (const float*)d_in[16];
    const float* w_hh_b   = (const float*)d_in[17];
    const float* b_b      = (const float*)d_in[18];
    const float* proj_w   = (const float*)d_in[19];
    const float* proj_b   = (const float*)d_in[20];
    const float* trans    = (const float*)d_in[21];

    char* ws = (char*)d_ws;
    float* pooled = (float*)(ws + OFF_POOL);
    float* x      = (float*)(ws + OFF_X);
    float* h_f    = (float*)(ws + OFF_HF);
    float* h_b    = (float*)(ws + OFF_HB);
    float* xs_f   = (float*)(ws + OFF_XSF);
    float* xs_b   = (float*)(ws + OFF_XSB);
    float* feats  = (float*)(ws + OFF_FEATS);
    float* wp_f   = (float*)(ws + OFF_WPF);
    float* wp_b   = (float*)(ws + OFF_WPB);
    float* lossb  = (float*)(ws + OFF_LOSSB);

    k_pack<<<1024, 256, 0, stream>>>(w_hh_f, wp_f);
    k_pack<<<1024, 256, 0, stream>>>(w_hh_b, wp_b);
    k_charcnn<<<BB * TT, 128, 0, stream>>>(batch_char, char_emb, conv_w, conv_b, pooled);
    k_concat<<<BB * TT, 128, 0, stream>>>(batch_word, batch_features, batch_recover,
                                          word_emb, feat_emb, pooled, x);
    k_gemm<<<dim3(G4 / BN, (BB * TT) / BM), 256, 0, stream>>>(x, w_ih_f, b_f, xs_f);
    k_gemm<<<dim3(G4 / BN, (BB * TT) / BM), 256, 0, stream>>>(x, w_ih_b, b_b, xs_b);
    k_lstm<<<128, 256, 0, stream>>>(xs_f, xs_b, wp_f, wp_b, batch_wordlen, h_f, h_b);
    k_proj<<<BB * TT, 64, 0, stream>>>(h_f, h_b, proj_w, proj_b, feats);
    k_crf<<<BB, 64, 0, stream>>>(feats, trans, batch_wordlen, batch_label,
                                 lossb, (float*)d_out + 1);
    k_loss<<<1, 64, 0, stream>>>(lossb, (float*)d_out);
}